// Round 2
// baseline (445.952 us; speedup 1.0000x reference)
//
#include <hip/hip_runtime.h>
#include <hip/hip_bf16.h>
#include <stdint.h>

#define N_NODES 8192
#define IN_F    256
#define OUT_F   64
#define NEG_SLOPE 0.2f
#define CAP     2048

static __device__ __forceinline__ float bf2f(unsigned short u) {
    union { unsigned int i; float f; } v;
    v.i = ((unsigned int)u) << 16;
    return v.f;
}

static __device__ __forceinline__ unsigned short f2bf(float f) {
    union { float f; unsigned int i; } v; v.f = f;
    unsigned int x = v.i;
    unsigned int lsb = (x >> 16) & 1u;
    x += 0x7FFFu + lsb;
    return (unsigned short)(x >> 16);
}

// ---------------------------------------------------------------------------
// flag[0]: adjacency width violations. bit0 = not 4-byte elems (words in
// {0,1,0x3F800000}), bit1 = not 2-byte (halves in {0,1,0x3F80}), bit2 = not
// 1-byte (bytes in {0,1}). Use: width 4 if !bit0, else 2 if !bit1, else 1.
// ---------------------------------------------------------------------------
__global__ void detect_adj_kernel(const unsigned int* __restrict__ w, int nwords,
                                  int* __restrict__ flag) {
    int viol = 0;
    for (int i = blockIdx.x * blockDim.x + threadIdx.x; i < nwords;
         i += gridDim.x * blockDim.x) {
        unsigned int v = w[i];
        if (v) {
            if (v != 1u && v != 0x3F800000u) viol |= 1;
            unsigned int h0 = v & 0xFFFFu, h1 = v >> 16;
            if ((h0 != 0u && h0 != 1u && h0 != 0x3F80u) ||
                (h1 != 0u && h1 != 1u && h1 != 0x3F80u)) viol |= 2;
            unsigned int b0 = v & 0xFFu, b1 = (v >> 8) & 0xFFu,
                         b2 = (v >> 16) & 0xFFu, b3 = v >> 24;
            if (b0 > 1u || b1 > 1u || b2 > 1u || b3 > 1u) viol |= 4;
        }
    }
    for (int o = 32; o; o >>= 1) viol |= __shfl_xor(viol, o, 64);
    if ((threadIdx.x & 63) == 0 && viol) atomicOr(&flag[0], viol);
}

// ---------------------------------------------------------------------------
// flag[1]: nonzero => node_features is fp32, not bf16.
// View buffer as u16 halves. bf16 N(0,1) data: every half has |val| < 8
// (exponent <= 129). fp32 data: mantissa low-halves are ~uniform 16-bit, so
// exponent >= 133 (|val| >= 64) occurs with p~0.48 per half -> certain hit.
// ---------------------------------------------------------------------------
__global__ void detect_x_kernel(const unsigned short* __restrict__ x, int n,
                                int* __restrict__ flag) {
    int viol = 0;
    for (int i = blockIdx.x * blockDim.x + threadIdx.x; i < n;
         i += gridDim.x * blockDim.x) {
        unsigned int e = ((unsigned int)x[i] >> 7) & 0xFFu;
        if (e >= 133u) viol = 1;
    }
    for (int o = 32; o; o >>= 1) viol |= __shfl_xor(viol, o, 64);
    if ((threadIdx.x & 63) == 0 && viol) atomicOr(&flag[1], 1);
}

// ---------------------------------------------------------------------------
// proj = X @ W (fp32 accum), s_i = proj @ a[:64], s_j = proj @ a[64:]
// 256 threads / block, 16 rows / block. Thread t: row = t>>4, cols (t&15)*4..+3.
// bf16 mode: W (32KB) + 16 X rows (8KB) staged in LDS.
// fp32 mode: read X/W directly from global (L1/L2-cached broadcasts), full
// fp32 precision (no rounding of inputs).
// ---------------------------------------------------------------------------
__global__ __launch_bounds__(256) void proj_kernel(
    const void* __restrict__ Xv, const void* __restrict__ Wv,
    const void* __restrict__ Av, const int* __restrict__ flag,
    float* __restrict__ proj, float* __restrict__ si, float* __restrict__ sj) {
    __shared__ unsigned short wL[IN_F * OUT_F];  // 32 KB
    __shared__ unsigned short xL[16 * IN_F];     // 8 KB
    __shared__ float aL[2 * OUT_F];

    int tid = threadIdx.x;
    int row0 = blockIdx.x * 16;
    int tc = tid & 15;
    int r  = tid >> 4;
    int c0 = tc * 4;
    int row = row0 + r;
    bool xf32 = (flag[1] != 0);

    float acc0 = 0.f, acc1 = 0.f, acc2 = 0.f, acc3 = 0.f;

    if (xf32) {
        const float* Xf = (const float*)Xv;
        const float* Wf = (const float*)Wv;
        const float* Af = (const float*)Av;
        if (tid < 2 * OUT_F) aL[tid] = Af[tid];
        __syncthreads();
        const float* xr = Xf + (size_t)row * IN_F;
#pragma unroll 4
        for (int k = 0; k < IN_F; ++k) {
            float x = xr[k];
            const float* wr = Wf + (size_t)k * OUT_F + c0;
            acc0 = fmaf(x, wr[0], acc0);
            acc1 = fmaf(x, wr[1], acc1);
            acc2 = fmaf(x, wr[2], acc2);
            acc3 = fmaf(x, wr[3], acc3);
        }
    } else {
        const unsigned short* Xh = (const unsigned short*)Xv;
        const unsigned short* Wh = (const unsigned short*)Wv;
        const unsigned short* Ah = (const unsigned short*)Av;
        for (int k = tid; k < IN_F * OUT_F; k += 256) wL[k] = Wh[k];
        if (tid < 2 * OUT_F) aL[tid] = bf2f(Ah[tid]);
        for (int k = tid; k < 16 * IN_F; k += 256)
            xL[k] = Xh[(size_t)row0 * IN_F + k];
        __syncthreads();
        const unsigned short* xr = &xL[r * IN_F];
#pragma unroll 4
        for (int k = 0; k < IN_F; ++k) {
            float x = bf2f(xr[k]);
            const unsigned short* wr = &wL[k * OUT_F + c0];
            acc0 = fmaf(x, bf2f(wr[0]), acc0);
            acc1 = fmaf(x, bf2f(wr[1]), acc1);
            acc2 = fmaf(x, bf2f(wr[2]), acc2);
            acc3 = fmaf(x, bf2f(wr[3]), acc3);
        }
    }

    *(float4*)&proj[(size_t)row * OUT_F + c0] = make_float4(acc0, acc1, acc2, acc3);

    float sa = acc0 * aL[c0] + acc1 * aL[c0 + 1] + acc2 * aL[c0 + 2] + acc3 * aL[c0 + 3];
    float sb = acc0 * aL[OUT_F + c0] + acc1 * aL[OUT_F + c0 + 1] +
               acc2 * aL[OUT_F + c0 + 2] + acc3 * aL[OUT_F + c0 + 3];
    for (int off = 8; off; off >>= 1) {
        sa += __shfl_xor(sa, off, 16);
        sb += __shfl_xor(sb, off, 16);
    }
    if (tc == 0) { si[row] = sa; sj[row] = sb; }
}

// ---------------------------------------------------------------------------
// Fused masked-softmax attention + h_out = attn @ proj, one block per row.
// ---------------------------------------------------------------------------
__global__ __launch_bounds__(256) void attn_kernel(
    const void* __restrict__ adj, const int* __restrict__ flag,
    const float* __restrict__ proj, const float* __restrict__ si_arr,
    const float* __restrict__ sj_arr, void* __restrict__ outv) {
    __shared__ int   s_idx[CAP];
    __shared__ float s_w[CAP];
    __shared__ int   s_cnt;
    __shared__ float red[256];
    __shared__ float hacc[OUT_F];

    int tid = threadIdx.x;
    int row = blockIdx.x;
    if (tid == 0) s_cnt = 0;
    __syncthreads();

    int f = flag[0];
    int width = (!(f & 1)) ? 4 : ((!(f & 2)) ? 2 : 1);
    bool f32o = (flag[1] != 0);
    float si = si_arr[row];
    float lmax = -3.0e38f;

    for (int chunk = 0; chunk < N_NODES / 1024; ++chunk) {
        int j0 = chunk * 1024 + tid * 4;
        unsigned int m0, m1, m2, m3;
        if (width == 4) {
            const uint4* p = (const uint4*)((const unsigned int*)adj + (size_t)row * N_NODES);
            uint4 v = p[j0 >> 2];
            m0 = v.x; m1 = v.y; m2 = v.z; m3 = v.w;
        } else if (width == 2) {
            const uint2* p = (const uint2*)((const unsigned short*)adj + (size_t)row * N_NODES);
            uint2 v = p[j0 >> 2];
            m0 = v.x & 0xFFFFu; m1 = v.x >> 16;
            m2 = v.y & 0xFFFFu; m3 = v.y >> 16;
        } else {
            const unsigned int* p = (const unsigned int*)((const unsigned char*)adj + (size_t)row * N_NODES);
            unsigned int v = p[j0 >> 2];
            m0 = v & 0xFFu; m1 = (v >> 8) & 0xFFu; m2 = (v >> 16) & 0xFFu; m3 = v >> 24;
        }
#pragma unroll
        for (int u = 0; u < 4; ++u) {
            unsigned int mu = (u == 0) ? m0 : (u == 1) ? m1 : (u == 2) ? m2 : m3;
            if (mu) {
                int j = j0 + u;
                float sc = si + sj_arr[j];
                sc = (sc >= 0.f) ? sc : NEG_SLOPE * sc;
                lmax = fmaxf(lmax, sc);
                int pos = atomicAdd(&s_cnt, 1);
                if (pos < CAP) { s_idx[pos] = j; s_w[pos] = sc; }
            }
        }
    }

    red[tid] = lmax;
    __syncthreads();
    int cnt = s_cnt;
    for (int s = 128; s > 0; s >>= 1) {
        if (tid < s) red[tid] = fmaxf(red[tid], red[tid + s]);
        __syncthreads();
    }
    float m = red[0];
    __syncthreads();

    if (cnt == 0) {
        // all-NEG_BIG row -> uniform softmax -> column mean of proj
        int c = tid & 63, part = tid >> 6;
        float acc = 0.f;
        for (int j = part; j < N_NODES; j += 4) acc += proj[(size_t)j * OUT_F + c];
        red[tid] = acc;
        __syncthreads();
        if (tid < OUT_F) {
            float h = (red[tid] + red[tid + 64] + red[tid + 128] + red[tid + 192]) * (1.0f / N_NODES);
            if (f32o) ((float*)outv)[(size_t)row * OUT_F + tid] = h;
            else ((unsigned short*)outv)[(size_t)row * OUT_F + tid] = f2bf(h);
        }
        return;
    }

    if (cnt <= CAP) {
        float psum = 0.f;
        for (int k = tid; k < cnt; k += 256) {
            float w = expf(s_w[k] - m);
            s_w[k] = w;
            psum += w;
        }
        red[tid] = psum;
        __syncthreads();
        for (int s = 128; s > 0; s >>= 1) {
            if (tid < s) red[tid] += red[tid + s];
            __syncthreads();
        }
        float denom = red[0];
        __syncthreads();

        int c = tid & 63, part = tid >> 6;
        float acc = 0.f;
        for (int k = part; k < cnt; k += 4)
            acc += s_w[k] * proj[(size_t)s_idx[k] * OUT_F + c];
        red[tid] = acc;
        __syncthreads();
        if (tid < OUT_F) {
            float h = (red[tid] + red[tid + 64] + red[tid + 128] + red[tid + 192]) / denom;
            if (f32o) ((float*)outv)[(size_t)row * OUT_F + tid] = h;
            else ((unsigned short*)outv)[(size_t)row * OUT_F + tid] = f2bf(h);
        }
        return;
    }

    // ---- overflow fallback (cnt > CAP): correct but slow; statistically never hit ----
    if (tid < OUT_F) hacc[tid] = 0.f;
    __syncthreads();
    float psum = 0.f;
    for (int chunk = 0; chunk < N_NODES / 1024; ++chunk) {
        int j0 = chunk * 1024 + tid * 4;
        unsigned int m0, m1, m2, m3;
        if (width == 4) {
            const uint4* p = (const uint4*)((const unsigned int*)adj + (size_t)row * N_NODES);
            uint4 v = p[j0 >> 2];
            m0 = v.x; m1 = v.y; m2 = v.z; m3 = v.w;
        } else if (width == 2) {
            const uint2* p = (const uint2*)((const unsigned short*)adj + (size_t)row * N_NODES);
            uint2 v = p[j0 >> 2];
            m0 = v.x & 0xFFFFu; m1 = v.x >> 16;
            m2 = v.y & 0xFFFFu; m3 = v.y >> 16;
        } else {
            const unsigned int* p = (const unsigned int*)((const unsigned char*)adj + (size_t)row * N_NODES);
            unsigned int v = p[j0 >> 2];
            m0 = v & 0xFFu; m1 = (v >> 8) & 0xFFu; m2 = (v >> 16) & 0xFFu; m3 = v >> 24;
        }
#pragma unroll
        for (int u = 0; u < 4; ++u) {
            unsigned int mu = (u == 0) ? m0 : (u == 1) ? m1 : (u == 2) ? m2 : m3;
            if (mu) {
                int j = j0 + u;
                float sc = si + sj_arr[j];
                sc = (sc >= 0.f) ? sc : NEG_SLOPE * sc;
                float w = expf(sc - m);
                psum += w;
                for (int c = 0; c < OUT_F; ++c)
                    atomicAdd(&hacc[c], w * proj[(size_t)j * OUT_F + c]);
            }
        }
    }
    red[tid] = psum;
    __syncthreads();
    for (int s = 128; s > 0; s >>= 1) {
        if (tid < s) red[tid] += red[tid + s];
        __syncthreads();
    }
    float denom = red[0];
    __syncthreads();
    if (tid < OUT_F) {
        float h = hacc[tid] / denom;
        if (f32o) ((float*)outv)[(size_t)row * OUT_F + tid] = h;
        else ((unsigned short*)outv)[(size_t)row * OUT_F + tid] = f2bf(h);
    }
}

extern "C" void kernel_launch(void* const* d_in, const int* in_sizes, int n_in,
                              void* d_out, int out_size, void* d_ws, size_t ws_size,
                              hipStream_t stream) {
    const void* X   = d_in[0];  // [8192,256] bf16 or fp32 (runtime-detected)
    const void* adj = d_in[1];  // [8192,8192] bool, width runtime-detected
    const void* W   = d_in[2];  // [256,64]
    const void* A   = d_in[3];  // [128,1]

    char* ws = (char*)d_ws;
    int*   flag = (int*)ws;                    // flag[0]=adj, flag[1]=x-fp32
    float* si   = (float*)(ws + 4096);
    float* sj   = (float*)(ws + 4096 + 32768);
    float* proj = (float*)(ws + 4096 + 65536);

    hipMemsetAsync(flag, 0, 8, stream);
    detect_adj_kernel<<<256, 256, 0, stream>>>((const unsigned int*)adj, 1 << 20, flag);
    detect_x_kernel<<<64, 256, 0, stream>>>((const unsigned short*)X, 1 << 16, flag);
    proj_kernel<<<N_NODES / 16, 256, 0, stream>>>(X, W, A, flag, proj, si, sj);
    attn_kernel<<<N_NODES, 256, 0, stream>>>(adj, flag, proj, si, sj, d_out);
}

// Round 3
// 445.212 us; speedup vs baseline: 1.0017x; 1.0017x over previous
//
#include <hip/hip_runtime.h>
#include <hip/hip_bf16.h>
#include <stdint.h>

#define N_NODES 8192
#define IN_F    256
#define OUT_F   64
#define NEG_SLOPE 0.2f
#define CAP     1024

static __device__ __forceinline__ float bf2f(unsigned short u) {
    union { unsigned int i; float f; } v;
    v.i = ((unsigned int)u) << 16;
    return v.f;
}
static __device__ __forceinline__ float bflo(unsigned int u) {
    union { unsigned int i; float f; } v; v.i = u << 16; return v.f;
}
static __device__ __forceinline__ float bfhi(unsigned int u) {
    union { unsigned int i; float f; } v; v.i = u & 0xFFFF0000u; return v.f;
}
static __device__ __forceinline__ unsigned short f2bf(float f) {
    union { float f; unsigned int i; } v; v.f = f;
    unsigned int x = v.i;
    unsigned int lsb = (x >> 16) & 1u;
    x += 0x7FFFu + lsb;
    return (unsigned short)(x >> 16);
}

// ---------------------------------------------------------------------------
// flag[0]: adjacency width violations. bit0 = not 4-byte elems (words in
// {0,1,0x3F800000}), bit1 = not 2-byte (halves in {0,1,0x3F80}), bit2 = not
// 1-byte (bytes in {0,1}). Use: width 4 if !bit0, else 2 if !bit1, else 1.
// ---------------------------------------------------------------------------
__global__ void detect_adj_kernel(const unsigned int* __restrict__ w, int nwords,
                                  int* __restrict__ flag) {
    int viol = 0;
    for (int i = blockIdx.x * blockDim.x + threadIdx.x; i < nwords;
         i += gridDim.x * blockDim.x) {
        unsigned int v = w[i];
        if (v) {
            if (v != 1u && v != 0x3F800000u) viol |= 1;
            unsigned int h0 = v & 0xFFFFu, h1 = v >> 16;
            if ((h0 != 0u && h0 != 1u && h0 != 0x3F80u) ||
                (h1 != 0u && h1 != 1u && h1 != 0x3F80u)) viol |= 2;
            unsigned int b0 = v & 0xFFu, b1 = (v >> 8) & 0xFFu,
                         b2 = (v >> 16) & 0xFFu, b3 = v >> 24;
            if (b0 > 1u || b1 > 1u || b2 > 1u || b3 > 1u) viol |= 4;
        }
    }
    for (int o = 32; o; o >>= 1) viol |= __shfl_xor(viol, o, 64);
    if ((threadIdx.x & 63) == 0 && viol) atomicOr(&flag[0], viol);
}

// flag[1]: nonzero => node_features is fp32 (u16 halves with exponent >= 133
// appear with p~0.5 in fp32 mantissa halves, never in bf16 N(0,1) data).
__global__ void detect_x_kernel(const unsigned short* __restrict__ x, int n,
                                int* __restrict__ flag) {
    int viol = 0;
    for (int i = blockIdx.x * blockDim.x + threadIdx.x; i < n;
         i += gridDim.x * blockDim.x) {
        unsigned int e = ((unsigned int)x[i] >> 7) & 0xFFu;
        if (e >= 133u) viol = 1;
    }
    for (int o = 32; o; o >>= 1) viol |= __shfl_xor(viol, o, 64);
    if ((threadIdx.x & 63) == 0 && viol) atomicOr(&flag[1], 1);
}

// ---------------------------------------------------------------------------
// proj = X @ W (fp32 accum), s_i = proj @ a[:64], s_j = proj @ a[64:]
// 256 thr / 16 rows per block. Thread t: row=t>>4, cols (t&15)*4..+3.
// bf16: X row via ds_read_b128 (8 bf16), W via ds_read_b64 (4 bf16).
// ---------------------------------------------------------------------------
__global__ __launch_bounds__(256) void proj_kernel(
    const void* __restrict__ Xv, const void* __restrict__ Wv,
    const void* __restrict__ Av, const int* __restrict__ flag,
    float* __restrict__ proj, float* __restrict__ si, float* __restrict__ sj) {
    __shared__ unsigned short wL[IN_F * OUT_F];  // 32 KB
    __shared__ unsigned short xL[16 * IN_F];     // 8 KB
    __shared__ float aL[2 * OUT_F];

    int tid = threadIdx.x;
    int row0 = blockIdx.x * 16;
    int tc = tid & 15;
    int r  = tid >> 4;
    int c0 = tc * 4;
    int row = row0 + r;
    bool xf32 = (flag[1] != 0);

    float acc0 = 0.f, acc1 = 0.f, acc2 = 0.f, acc3 = 0.f;

    if (xf32) {
        const float* Xf = (const float*)Xv;
        const float* Wf = (const float*)Wv;
        const float* Af = (const float*)Av;
        if (tid < 2 * OUT_F) aL[tid] = Af[tid];
        __syncthreads();
        const float4* xr = (const float4*)(Xf + (size_t)row * IN_F);
#pragma unroll 2
        for (int kv = 0; kv < IN_F / 4; ++kv) {
            float4 xq = xr[kv];
#pragma unroll
            for (int t = 0; t < 4; ++t) {
                float x = (t == 0) ? xq.x : (t == 1) ? xq.y : (t == 2) ? xq.z : xq.w;
                float4 wq = *(const float4*)(Wf + (size_t)(kv * 4 + t) * OUT_F + c0);
                acc0 = fmaf(x, wq.x, acc0);
                acc1 = fmaf(x, wq.y, acc1);
                acc2 = fmaf(x, wq.z, acc2);
                acc3 = fmaf(x, wq.w, acc3);
            }
        }
    } else {
        const unsigned short* Xh = (const unsigned short*)Xv;
        const unsigned short* Wh = (const unsigned short*)Wv;
        const unsigned short* Ah = (const unsigned short*)Av;
        // vector staging: W = 1024 uint4, X tile = 512 uint4
        for (int i = tid; i < (IN_F * OUT_F) / 8; i += 256)
            ((uint4*)wL)[i] = ((const uint4*)Wh)[i];
        for (int i = tid; i < (16 * IN_F) / 8; i += 256)
            ((uint4*)xL)[i] = ((const uint4*)(Xh + (size_t)row0 * IN_F))[i];
        if (tid < 2 * OUT_F) aL[tid] = bf2f(Ah[tid]);
        __syncthreads();

        const uint4* xrv = (const uint4*)&xL[r * IN_F];
#pragma unroll 4
        for (int kv = 0; kv < IN_F / 8; ++kv) {
            uint4 xq = xrv[kv];  // 8 bf16
#pragma unroll
            for (int h = 0; h < 4; ++h) {
                unsigned int xp = (h == 0) ? xq.x : (h == 1) ? xq.y : (h == 2) ? xq.z : xq.w;
                int k0 = kv * 8 + h * 2;
                uint2 w0 = *(const uint2*)&wL[(k0 + 0) * OUT_F + c0];
                uint2 w1 = *(const uint2*)&wL[(k0 + 1) * OUT_F + c0];
                float xa = bflo(xp), xb = bfhi(xp);
                acc0 = fmaf(xa, bflo(w0.x), acc0);
                acc1 = fmaf(xa, bfhi(w0.x), acc1);
                acc2 = fmaf(xa, bflo(w0.y), acc2);
                acc3 = fmaf(xa, bfhi(w0.y), acc3);
                acc0 = fmaf(xb, bflo(w1.x), acc0);
                acc1 = fmaf(xb, bfhi(w1.x), acc1);
                acc2 = fmaf(xb, bflo(w1.y), acc2);
                acc3 = fmaf(xb, bfhi(w1.y), acc3);
            }
        }
    }

    *(float4*)&proj[(size_t)row * OUT_F + c0] = make_float4(acc0, acc1, acc2, acc3);

    float sa = acc0 * aL[c0] + acc1 * aL[c0 + 1] + acc2 * aL[c0 + 2] + acc3 * aL[c0 + 3];
    float sb = acc0 * aL[OUT_F + c0] + acc1 * aL[OUT_F + c0 + 1] +
               acc2 * aL[OUT_F + c0 + 2] + acc3 * aL[OUT_F + c0 + 3];
    for (int off = 8; off; off >>= 1) {
        sa += __shfl_xor(sa, off, 16);
        sb += __shfl_xor(sb, off, 16);
    }
    if (tc == 0) { si[row] = sa; sj[row] = sb; }
}

// ---------------------------------------------------------------------------
// Fused masked softmax + h_out = attn @ proj. One block (256 thr) per row.
// Ballot-compaction of neighbors into LDS, then exp/sum, then gather.
// __launch_bounds__(256,4): cap VGPR<=128 so cold paths can't kill occupancy.
// ---------------------------------------------------------------------------
__global__ __launch_bounds__(256, 4) void attn_kernel(
    const void* __restrict__ adj, const int* __restrict__ flag,
    const float* __restrict__ proj, const float* __restrict__ si_arr,
    const float* __restrict__ sj_arr, void* __restrict__ outv) {
    __shared__ int   s_idx[CAP];
    __shared__ float s_w[CAP];
    __shared__ int   s_cnt;
    __shared__ float red[256];
    __shared__ float hacc[OUT_F];

    int tid = threadIdx.x;
    int lane = tid & 63;
    int row = blockIdx.x;
    if (tid == 0) s_cnt = 0;
    __syncthreads();

    int f = flag[0];
    int width = (!(f & 1)) ? 4 : ((!(f & 2)) ? 2 : 1);
    bool f32o = (flag[1] != 0);
    float si = si_arr[row];
    float lmax = -3.0e38f;

    for (int chunk = 0; chunk < N_NODES / 1024; ++chunk) {
        int j0 = chunk * 1024 + tid * 4;
        unsigned int m0, m1, m2, m3;
        if (width == 4) {
            const uint4* p = (const uint4*)((const unsigned int*)adj + (size_t)row * N_NODES);
            uint4 v = p[j0 >> 2];
            m0 = v.x; m1 = v.y; m2 = v.z; m3 = v.w;
        } else if (width == 2) {
            const uint2* p = (const uint2*)((const unsigned short*)adj + (size_t)row * N_NODES);
            uint2 v = p[j0 >> 2];
            m0 = v.x & 0xFFFFu; m1 = v.x >> 16;
            m2 = v.y & 0xFFFFu; m3 = v.y >> 16;
        } else {
            const unsigned int* p = (const unsigned int*)((const unsigned char*)adj + (size_t)row * N_NODES);
            unsigned int v = p[j0 >> 2];
            m0 = v & 0xFFu; m1 = (v >> 8) & 0xFFu; m2 = (v >> 16) & 0xFFu; m3 = v >> 24;
        }
#pragma unroll
        for (int u = 0; u < 4; ++u) {
            unsigned int mu = (u == 0) ? m0 : (u == 1) ? m1 : (u == 2) ? m2 : m3;
            bool hit = (mu != 0u);
            unsigned long long b = __ballot(hit);
            if (b) {  // wave-uniform
                int base;
                if (lane == 0) base = atomicAdd(&s_cnt, __popcll(b));
                base = __shfl(base, 0, 64);
                if (hit) {
                    int j = j0 + u;
                    float sc = si + sj_arr[j];
                    sc = (sc >= 0.f) ? sc : NEG_SLOPE * sc;
                    lmax = fmaxf(lmax, sc);
                    int pos = base + __popcll(b & ((1ull << lane) - 1ull));
                    if (pos < CAP) { s_idx[pos] = j; s_w[pos] = sc; }
                }
            }
        }
    }

    red[tid] = lmax;
    __syncthreads();
    int cnt = s_cnt;
    for (int s = 128; s > 0; s >>= 1) {
        if (tid < s) red[tid] = fmaxf(red[tid], red[tid + s]);
        __syncthreads();
    }
    float m = red[0];
    __syncthreads();

    if (cnt == 0) {
        // all-NEG_BIG row -> uniform softmax -> column mean of proj
        int c = tid & 63, part = tid >> 6;
        float acc = 0.f;
#pragma unroll 1
        for (int j = part; j < N_NODES; j += 4) acc += proj[(size_t)j * OUT_F + c];
        red[tid] = acc;
        __syncthreads();
        if (tid < OUT_F) {
            float h = (red[tid] + red[tid + 64] + red[tid + 128] + red[tid + 192]) * (1.0f / N_NODES);
            if (f32o) ((float*)outv)[(size_t)row * OUT_F + tid] = h;
            else ((unsigned short*)outv)[(size_t)row * OUT_F + tid] = f2bf(h);
        }
        return;
    }

    if (cnt <= CAP) {
        float psum = 0.f;
        for (int k = tid; k < cnt; k += 256) {
            float w = expf(s_w[k] - m);
            s_w[k] = w;
            psum += w;
        }
        red[tid] = psum;
        __syncthreads();
        for (int s = 128; s > 0; s >>= 1) {
            if (tid < s) red[tid] += red[tid + s];
            __syncthreads();
        }
        float denom = red[0];
        __syncthreads();

        int c = tid & 63, part = tid >> 6;
        float acc = 0.f;
        for (int k = part; k < cnt; k += 4)
            acc += s_w[k] * proj[(size_t)s_idx[k] * OUT_F + c];
        red[tid] = acc;
        __syncthreads();
        if (tid < OUT_F) {
            float h = (red[tid] + red[tid + 64] + red[tid + 128] + red[tid + 192]) / denom;
            if (f32o) ((float*)outv)[(size_t)row * OUT_F + tid] = h;
            else ((unsigned short*)outv)[(size_t)row * OUT_F + tid] = f2bf(h);
        }
        return;
    }

    // ---- overflow fallback (cnt > CAP): correct but slow; never hit in practice ----
    if (tid < OUT_F) hacc[tid] = 0.f;
    __syncthreads();
    float psum = 0.f;
#pragma unroll 1
    for (int chunk = 0; chunk < N_NODES / 1024; ++chunk) {
        int j0 = chunk * 1024 + tid * 4;
        unsigned int m0, m1, m2, m3;
        if (width == 4) {
            const uint4* p = (const uint4*)((const unsigned int*)adj + (size_t)row * N_NODES);
            uint4 v = p[j0 >> 2];
            m0 = v.x; m1 = v.y; m2 = v.z; m3 = v.w;
        } else if (width == 2) {
            const uint2* p = (const uint2*)((const unsigned short*)adj + (size_t)row * N_NODES);
            uint2 v = p[j0 >> 2];
            m0 = v.x & 0xFFFFu; m1 = v.x >> 16;
            m2 = v.y & 0xFFFFu; m3 = v.y >> 16;
        } else {
            const unsigned int* p = (const unsigned int*)((const unsigned char*)adj + (size_t)row * N_NODES);
            unsigned int v = p[j0 >> 2];
            m0 = v & 0xFFu; m1 = (v >> 8) & 0xFFu; m2 = (v >> 16) & 0xFFu; m3 = v >> 24;
        }
#pragma unroll 1
        for (int u = 0; u < 4; ++u) {
            unsigned int mu = (u == 0) ? m0 : (u == 1) ? m1 : (u == 2) ? m2 : m3;
            if (mu) {
                int j = j0 + u;
                float sc = si + sj_arr[j];
                sc = (sc >= 0.f) ? sc : NEG_SLOPE * sc;
                float w = expf(sc - m);
                psum += w;
#pragma unroll 1
                for (int c = 0; c < OUT_F; ++c)
                    atomicAdd(&hacc[c], w * proj[(size_t)j * OUT_F + c]);
            }
        }
    }
    red[tid] = psum;
    __syncthreads();
    for (int s = 128; s > 0; s >>= 1) {
        if (tid < s) red[tid] += red[tid + s];
        __syncthreads();
    }
    float denom = red[0];
    __syncthreads();
    if (tid < OUT_F) {
        float h = hacc[tid] / denom;
        if (f32o) ((float*)outv)[(size_t)row * OUT_F + tid] = h;
        else ((unsigned short*)outv)[(size_t)row * OUT_F + tid] = f2bf(h);
    }
}

extern "C" void kernel_launch(void* const* d_in, const int* in_sizes, int n_in,
                              void* d_out, int out_size, void* d_ws, size_t ws_size,
                              hipStream_t stream) {
    const void* X   = d_in[0];  // [8192,256] bf16 or fp32 (runtime-detected)
    const void* adj = d_in[1];  // [8192,8192] bool, width runtime-detected
    const void* W   = d_in[2];  // [256,64]
    const void* A   = d_in[3];  // [128,1]

    char* ws = (char*)d_ws;
    int*   flag = (int*)ws;                    // flag[0]=adj, flag[1]=x-fp32
    float* si   = (float*)(ws + 4096);
    float* sj   = (float*)(ws + 4096 + 32768);
    float* proj = (float*)(ws + 4096 + 65536);

    hipMemsetAsync(flag, 0, 8, stream);
    detect_adj_kernel<<<128, 256, 0, stream>>>((const unsigned int*)adj, 1 << 18, flag);
    detect_x_kernel<<<64, 256, 0, stream>>>((const unsigned short*)X, 1 << 16, flag);
    proj_kernel<<<N_NODES / 16, 256, 0, stream>>>(X, W, A, flag, proj, si, sj);
    attn_kernel<<<N_NODES, 256, 0, stream>>>(adj, flag, proj, si, sj, d_out);
}